// Round 1
// baseline (688.292 us; speedup 1.0000x reference)
//
#include <hip/hip_runtime.h>

// Problem constants (asserted implicitly via sizes):
//   E = in_sizes[0]/2, IN = 128, OUT = 256, N = out_size/OUT
#define IN_CH 128
#define OUT_CH 256
#define NPB 8          // nodes per block in gather/project
#define BLK 256        // threads per block (4 waves)
#define BLK_SCAN 1024  // elements per scan block

__global__ void zero_i32(int* __restrict__ p, int n) {
  int i = blockIdx.x * blockDim.x + threadIdx.x;
  if (i < n) p[i] = 0;
}

__global__ void hist_kernel(const int* __restrict__ col, int E, int* __restrict__ count) {
  int i = blockIdx.x * blockDim.x + threadIdx.x;
  if (i < E) atomicAdd(&count[col[i]], 1);
}

// Per-block exclusive scan of count -> excl, block totals -> bsum
__global__ __launch_bounds__(BLK_SCAN) void scan_block_kernel(
    const int* __restrict__ count, int N, int* __restrict__ excl, int* __restrict__ bsum) {
  __shared__ int tmp[BLK_SCAN];
  const int tid = threadIdx.x;
  const int i = blockIdx.x * BLK_SCAN + tid;
  int v = (i < N) ? count[i] : 0;
  tmp[tid] = v;
  __syncthreads();
  for (int d = 1; d < BLK_SCAN; d <<= 1) {
    int t = (tid >= d) ? tmp[tid - d] : 0;
    __syncthreads();
    tmp[tid] += t;
    __syncthreads();
  }
  if (i < N) excl[i] = tmp[tid] - v;       // exclusive within block
  if (tid == BLK_SCAN - 1) bsum[blockIdx.x] = tmp[tid];
}

// Exclusive scan of block sums (handles nb up to many chunks of 256)
__global__ void scan_bsum_kernel(int* __restrict__ bsum, int nb) {
  __shared__ int tmp[256];
  const int tid = threadIdx.x;
  int run = 0;
  for (int s = 0; s < nb; s += 256) {
    int v = (s + tid < nb) ? bsum[s + tid] : 0;
    tmp[tid] = v;
    __syncthreads();
    for (int d = 1; d < 256; d <<= 1) {
      int t = (tid >= d) ? tmp[tid - d] : 0;
      __syncthreads();
      tmp[tid] += t;
      __syncthreads();
    }
    if (s + tid < nb) bsum[s + tid] = run + tmp[tid] - v;  // exclusive
    run += tmp[255];
    __syncthreads();
  }
}

// offsets[i] = excl[i] + bsum[block]; cursor[i] = offsets[i]
__global__ void add_offsets_kernel(int* __restrict__ excl, const int* __restrict__ bsum,
                                   int* __restrict__ cursor, int N) {
  int i = blockIdx.x * blockDim.x + threadIdx.x;
  if (i < N) {
    int o = excl[i] + bsum[i / BLK_SCAN];
    excl[i] = o;
    cursor[i] = o;
  }
}

__global__ void scatter_kernel(const int* __restrict__ col, int E,
                               int* __restrict__ cursor, int* __restrict__ sorted) {
  int i = blockIdx.x * blockDim.x + threadIdx.x;
  if (i < E) {
    int c = col[i];
    int pos = atomicAdd(&cursor[c], 1);
    sorted[pos] = i;
  }
}

// Fused gather (segment-sum) + projection.
// Phase 1: wave per node; each iteration loads TWO 512B rows (lanes 0-31 edge i,
//          lanes 32-63 edge i+1), float4 per lane; halves combined via shfl.
// Phase 2: thread t = output channel; dot(agg[g][:], W[t][:]) + b[t].
__global__ __launch_bounds__(BLK) void gather_project_kernel(
    const float* __restrict__ te, const int* __restrict__ offsets,
    const int* __restrict__ cend, const int* __restrict__ sorted,
    const float* __restrict__ W, const float* __restrict__ bias,
    float* __restrict__ out, int N) {
  __shared__ float agg[NPB][IN_CH];  // 4 KB
  const int wave = threadIdx.x >> 6;
  const int lane = threadIdx.x & 63;
  const int half = lane >> 5;   // 0: edge i, 1: edge i+1
  const int cl = lane & 31;     // channel group: floats cl*4 .. cl*4+3
  const int base = blockIdx.x * NPB;

  for (int g = wave; g < NPB; g += (BLK / 64)) {
    const int n = base + g;
    float ax = 0.f, ay = 0.f, az = 0.f, aw = 0.f;
    if (n < N) {
      const int s = offsets[n];
      const int e = cend[n];
      int i = s;
      for (; i + 2 <= e; i += 2) {
        const int eid = sorted[i + half];
        const float4 v = *(const float4*)(te + (size_t)eid * IN_CH + cl * 4);
        ax += v.x; ay += v.y; az += v.z; aw += v.w;
      }
      if (i < e && half == 0) {
        const int eid = sorted[i];
        const float4 v = *(const float4*)(te + (size_t)eid * IN_CH + cl * 4);
        ax += v.x; ay += v.y; az += v.z; aw += v.w;
      }
    }
    // combine half 1 into half 0
    ax += __shfl_down(ax, 32);
    ay += __shfl_down(ay, 32);
    az += __shfl_down(az, 32);
    aw += __shfl_down(aw, 32);
    if (half == 0) {
      float4 r; r.x = ax; r.y = ay; r.z = az; r.w = aw;
      *(float4*)(&agg[g][cl * 4]) = r;
    }
  }
  __syncthreads();

  // Phase 2: projection
  const int t = threadIdx.x;  // == output channel (BLK == OUT_CH)
  float acc[NPB];
#pragma unroll
  for (int g = 0; g < NPB; ++g) acc[g] = 0.f;
  const float4* __restrict__ Wr = (const float4*)(W + (size_t)t * IN_CH);
#pragma unroll 4
  for (int c4 = 0; c4 < IN_CH / 4; ++c4) {
    const float4 w = Wr[c4];
#pragma unroll
    for (int g = 0; g < NPB; ++g) {
      const float4 a = *(const float4*)(&agg[g][c4 * 4]);
      acc[g] = fmaf(w.x, a.x, fmaf(w.y, a.y, fmaf(w.z, a.z, fmaf(w.w, a.w, acc[g]))));
    }
  }
  const float bv = bias[t];
#pragma unroll
  for (int g = 0; g < NPB; ++g) {
    const int n = base + g;
    if (n < N) out[(size_t)n * OUT_CH + t] = acc[g] + bv;
  }
}

extern "C" void kernel_launch(void* const* d_in, const int* in_sizes, int n_in,
                              void* d_out, int out_size, void* d_ws, size_t ws_size,
                              hipStream_t stream) {
  const int* edge_index = (const int*)d_in[0];
  const float* te       = (const float*)d_in[1];
  // d_in[2] = num_nodes (device scalar, unused; N derived from out_size)
  const float* W        = (const float*)d_in[3];
  const float* bias     = (const float*)d_in[4];
  float* out            = (float*)d_out;

  const int E = in_sizes[0] / 2;
  const int N = out_size / OUT_CH;
  const int* col = edge_index + E;  // edge_index[1]

  // Workspace layout (ints)
  int* ws      = (int*)d_ws;
  int* count   = ws;            // N
  int* offsets = ws + N;        // N  (excl -> offsets, in place)
  int* cursor  = ws + 2 * N;    // N  (becomes bucket end after scatter)
  int* bsum    = ws + 3 * N;    // nb (padded region of 4096)
  int* sorted  = ws + 3 * N + 4096;  // E

  const int nb = (N + BLK_SCAN - 1) / BLK_SCAN;

  hipLaunchKernelGGL(zero_i32, dim3((N + 255) / 256), dim3(256), 0, stream, count, N);
  hipLaunchKernelGGL(hist_kernel, dim3((E + 255) / 256), dim3(256), 0, stream, col, E, count);
  hipLaunchKernelGGL(scan_block_kernel, dim3(nb), dim3(BLK_SCAN), 0, stream, count, N, offsets, bsum);
  hipLaunchKernelGGL(scan_bsum_kernel, dim3(1), dim3(256), 0, stream, bsum, nb);
  hipLaunchKernelGGL(add_offsets_kernel, dim3((N + 255) / 256), dim3(256), 0, stream,
                     offsets, bsum, cursor, N);
  hipLaunchKernelGGL(scatter_kernel, dim3((E + 255) / 256), dim3(256), 0, stream, col, E, cursor, sorted);
  hipLaunchKernelGGL(gather_project_kernel, dim3((N + NPB - 1) / NPB), dim3(BLK), 0, stream,
                     te, offsets, cursor, sorted, W, bias, out, N);
}

// Round 2
// 532.587 us; speedup vs baseline: 1.2924x; 1.2924x over previous
//
#include <hip/hip_runtime.h>

#define IN_CH 128
#define OUT_CH 256
#define NPB 8          // nodes per block == half-waves per block
#define BLK 256        // threads per block (4 waves, 8 half-waves)
#define BLK_SCAN 1024

__global__ void zero_i32(int* __restrict__ p, int n) {
  int i = blockIdx.x * blockDim.x + threadIdx.x;
  if (i < n) p[i] = 0;
}

__global__ void hist_kernel(const int* __restrict__ col, int E, int* __restrict__ count) {
  int i = blockIdx.x * blockDim.x + threadIdx.x;
  if (i < E) atomicAdd(&count[col[i]], 1);
}

__global__ __launch_bounds__(BLK_SCAN) void scan_block_kernel(
    const int* __restrict__ count, int N, int* __restrict__ excl, int* __restrict__ bsum) {
  __shared__ int tmp[BLK_SCAN];
  const int tid = threadIdx.x;
  const int i = blockIdx.x * BLK_SCAN + tid;
  int v = (i < N) ? count[i] : 0;
  tmp[tid] = v;
  __syncthreads();
  for (int d = 1; d < BLK_SCAN; d <<= 1) {
    int t = (tid >= d) ? tmp[tid - d] : 0;
    __syncthreads();
    tmp[tid] += t;
    __syncthreads();
  }
  if (i < N) excl[i] = tmp[tid] - v;
  if (tid == BLK_SCAN - 1) bsum[blockIdx.x] = tmp[tid];
}

__global__ void scan_bsum_kernel(int* __restrict__ bsum, int nb) {
  __shared__ int tmp[256];
  const int tid = threadIdx.x;
  int run = 0;
  for (int s = 0; s < nb; s += 256) {
    int v = (s + tid < nb) ? bsum[s + tid] : 0;
    tmp[tid] = v;
    __syncthreads();
    for (int d = 1; d < 256; d <<= 1) {
      int t = (tid >= d) ? tmp[tid - d] : 0;
      __syncthreads();
      tmp[tid] += t;
      __syncthreads();
    }
    if (s + tid < nb) bsum[s + tid] = run + tmp[tid] - v;
    run += tmp[255];
    __syncthreads();
  }
}

__global__ void add_offsets_kernel(int* __restrict__ excl, const int* __restrict__ bsum,
                                   int* __restrict__ cursor, int N) {
  int i = blockIdx.x * blockDim.x + threadIdx.x;
  if (i < N) {
    int o = excl[i] + bsum[i / BLK_SCAN];
    excl[i] = o;
    cursor[i] = o;
  }
}

__global__ void scatter_kernel(const int* __restrict__ col, int E,
                               int* __restrict__ cursor, int* __restrict__ sorted) {
  int i = blockIdx.x * blockDim.x + threadIdx.x;
  if (i < E) {
    int c = col[i];
    int pos = atomicAdd(&cursor[c], 1);
    sorted[pos] = i;
  }
}

// Phase 1: one node per HALF-WAVE (32 lanes x float4 = one 128-ch row).
//   - cooperative eid fetch: lanes 0..7 load sorted[i..i+7], broadcast via shfl
//   - 8 independent clamped row loads issued back-to-back (8 KB MLP per wave)
//   - predication by 0/1 scale fma, NOT branches (keeps loads unfenced)
// Phase 2: thread t = output channel; dot(agg[g][:], W[t][:]) + b[t].
__global__ __launch_bounds__(BLK) void gather_project_kernel(
    const float* __restrict__ te, const int* __restrict__ offsets,
    const int* __restrict__ cend, const int* __restrict__ sorted,
    const float* __restrict__ W, const float* __restrict__ bias,
    float* __restrict__ out, int N) {
  __shared__ float agg[NPB][IN_CH];  // 4 KB
  const int g   = threadIdx.x >> 5;   // half-wave id 0..7 == node slot
  const int h32 = threadIdx.x & 31;   // lane within half-wave
  const int base = blockIdx.x * NPB;
  const int n = base + g;

  float ax = 0.f, ay = 0.f, az = 0.f, aw = 0.f;
  if (n < N) {
    const int s = offsets[n];
    const int e = cend[n];
    for (int i = s; i < e; i += 8) {
      int my = 0;
      if (h32 < 8) {
        int idx = i + h32;
        my = sorted[idx < e ? idx : (e - 1)];
      }
      const int rem = e - i;
      const size_t co = (size_t)(h32 * 4);
#define EID(j) __shfl(my, j, 32)
      const float4 t0 = *(const float4*)(te + (size_t)EID(0) * IN_CH + co);
      const float4 t1 = *(const float4*)(te + (size_t)EID(1) * IN_CH + co);
      const float4 t2 = *(const float4*)(te + (size_t)EID(2) * IN_CH + co);
      const float4 t3 = *(const float4*)(te + (size_t)EID(3) * IN_CH + co);
      const float4 t4 = *(const float4*)(te + (size_t)EID(4) * IN_CH + co);
      const float4 t5 = *(const float4*)(te + (size_t)EID(5) * IN_CH + co);
      const float4 t6 = *(const float4*)(te + (size_t)EID(6) * IN_CH + co);
      const float4 t7 = *(const float4*)(te + (size_t)EID(7) * IN_CH + co);
#undef EID
      const float c1 = (rem > 1) ? 1.f : 0.f;
      const float c2 = (rem > 2) ? 1.f : 0.f;
      const float c3 = (rem > 3) ? 1.f : 0.f;
      const float c4 = (rem > 4) ? 1.f : 0.f;
      const float c5 = (rem > 5) ? 1.f : 0.f;
      const float c6 = (rem > 6) ? 1.f : 0.f;
      const float c7 = (rem > 7) ? 1.f : 0.f;
      ax += t0.x; ay += t0.y; az += t0.z; aw += t0.w;
      ax = fmaf(c1, t1.x, ax); ay = fmaf(c1, t1.y, ay); az = fmaf(c1, t1.z, az); aw = fmaf(c1, t1.w, aw);
      ax = fmaf(c2, t2.x, ax); ay = fmaf(c2, t2.y, ay); az = fmaf(c2, t2.z, az); aw = fmaf(c2, t2.w, aw);
      ax = fmaf(c3, t3.x, ax); ay = fmaf(c3, t3.y, ay); az = fmaf(c3, t3.z, az); aw = fmaf(c3, t3.w, aw);
      ax = fmaf(c4, t4.x, ax); ay = fmaf(c4, t4.y, ay); az = fmaf(c4, t4.z, az); aw = fmaf(c4, t4.w, aw);
      ax = fmaf(c5, t5.x, ax); ay = fmaf(c5, t5.y, ay); az = fmaf(c5, t5.z, az); aw = fmaf(c5, t5.w, aw);
      ax = fmaf(c6, t6.x, ax); ay = fmaf(c6, t6.y, ay); az = fmaf(c6, t6.z, az); aw = fmaf(c6, t6.w, aw);
      ax = fmaf(c7, t7.x, ax); ay = fmaf(c7, t7.y, ay); az = fmaf(c7, t7.z, az); aw = fmaf(c7, t7.w, aw);
    }
  }
  {
    float4 r; r.x = ax; r.y = ay; r.z = az; r.w = aw;
    *(float4*)(&agg[g][h32 * 4]) = r;
  }
  __syncthreads();

  // Phase 2: projection (BLK == OUT_CH; thread t = output channel)
  const int t = threadIdx.x;
  float acc[NPB];
#pragma unroll
  for (int gg = 0; gg < NPB; ++gg) acc[gg] = 0.f;
  const float4* __restrict__ Wr = (const float4*)(W + (size_t)t * IN_CH);
#pragma unroll 4
  for (int c4i = 0; c4i < IN_CH / 4; ++c4i) {
    const float4 w = Wr[c4i];
#pragma unroll
    for (int gg = 0; gg < NPB; ++gg) {
      const float4 a = *(const float4*)(&agg[gg][c4i * 4]);
      acc[gg] = fmaf(w.x, a.x, fmaf(w.y, a.y, fmaf(w.z, a.z, fmaf(w.w, a.w, acc[gg]))));
    }
  }
  const float bv = bias[t];
#pragma unroll
  for (int gg = 0; gg < NPB; ++gg) {
    const int nn = base + gg;
    if (nn < N) out[(size_t)nn * OUT_CH + t] = acc[gg] + bv;
  }
}

extern "C" void kernel_launch(void* const* d_in, const int* in_sizes, int n_in,
                              void* d_out, int out_size, void* d_ws, size_t ws_size,
                              hipStream_t stream) {
  const int* edge_index = (const int*)d_in[0];
  const float* te       = (const float*)d_in[1];
  const float* W        = (const float*)d_in[3];
  const float* bias     = (const float*)d_in[4];
  float* out            = (float*)d_out;

  const int E = in_sizes[0] / 2;
  const int N = out_size / OUT_CH;
  const int* col = edge_index + E;

  int* ws      = (int*)d_ws;
  int* count   = ws;
  int* offsets = ws + N;
  int* cursor  = ws + 2 * N;
  int* bsum    = ws + 3 * N;
  int* sorted  = ws + 3 * N + 4096;

  const int nb = (N + BLK_SCAN - 1) / BLK_SCAN;

  hipLaunchKernelGGL(zero_i32, dim3((N + 255) / 256), dim3(256), 0, stream, count, N);
  hipLaunchKernelGGL(hist_kernel, dim3((E + 255) / 256), dim3(256), 0, stream, col, E, count);
  hipLaunchKernelGGL(scan_block_kernel, dim3(nb), dim3(BLK_SCAN), 0, stream, count, N, offsets, bsum);
  hipLaunchKernelGGL(scan_bsum_kernel, dim3(1), dim3(256), 0, stream, bsum, nb);
  hipLaunchKernelGGL(add_offsets_kernel, dim3((N + 255) / 256), dim3(256), 0, stream,
                     offsets, bsum, cursor, N);
  hipLaunchKernelGGL(scatter_kernel, dim3((E + 255) / 256), dim3(256), 0, stream, col, E, cursor, sorted);
  hipLaunchKernelGGL(gather_project_kernel, dim3((N + NPB - 1) / NPB), dim3(BLK), 0, stream,
                     te, offsets, cursor, sorted, W, bias, out, N);
}